// Round 9
// baseline (69.570 us; speedup 1.0000x reference)
//
#include <hip/hip_runtime.h>
#include <hip/hip_fp16.h>
#include <math.h>

#define N_CELLS 65536
#define HIDDEN  128
#define IN_DIM  64
#define MAX_DEG 6

#define WPB    4                    // waves per block (k_main)
#define NPB    32                   // nodes per block
#define NBLK   (N_CELLS/NPB)        // 2048 main-kernel blocks
#define CHUNK  4                    // iterations per wave (2 nodes per iter)
#define NXCD   8

#define INV2PI 0.15915494309189535f

__device__ __forceinline__ void fsincos(float x, float& s, float& c) {
    const float r = x * INV2PI;                     // revolutions for v_sin/v_cos
    s = __builtin_amdgcn_sinf(r);
    c = __builtin_amdgcn_cosf(r);
}

// ---------------- ws offsets (~36.5 MB) ----------------
#define WS_PP    0                                  // 128 f32
#define WS_FLAG  512                                // 1 int
#define WS_STR   1024                               // 65536 f32
#define WS_S     (1024 + N_CELLS*4)                 // 65536 x 512B fp16 states (32 MB)
#define WS_ADJ   (WS_S + (size_t)N_CELLS*512)       // 65536 x 32B adj records (2 MB)
#define WS_P     (WS_ADJ + (size_t)N_CELLS*32)      // 256 x NBLK f32 (2 MB)
#define WS_SA    (WS_P + 256*NBLK*4)                // NBLK f32
#define WS_SA2   (WS_SA + NBLK*4)                   // NBLK f32
#define WS_MEAN  (WS_SA2 + NBLK*4)                  // 256 f32

// k_pre: S[i][h] = (R,I) fp16 = amp*e^{i(phase+0.1vel)}; strength[i]=sum_h amp.
// Last block: prep (pp, mask-layout flag).
__global__ __launch_bounds__(256) void k_pre(
    const float* __restrict__ amp, const float* __restrict__ phase,
    const float* __restrict__ vel,
    const float* __restrict__ x, const float* __restrict__ W_in,
    const float* __restrict__ b_in, const unsigned char* __restrict__ maskb,
    int4* __restrict__ S, float* __restrict__ strength,
    float* __restrict__ pp, int* __restrict__ flag)
{
    const int tid = threadIdx.x;
    if (blockIdx.x < N_CELLS/8) {
        const int node = blockIdx.x*8 + (tid >> 5);
        const int hl   = tid & 31;
        const size_t ro = (size_t)node*HIDDEN + 4*hl;
        const float4 a = *(const float4*)(amp   + ro);
        const float4 p = *(const float4*)(phase + ro);
        const float4 v = *(const float4*)(vel   + ro);
        float s0,c0,s1,c1,s2,c2,s3,c3;
        fsincos(fmaf(0.1f, v.x, p.x), s0, c0);
        fsincos(fmaf(0.1f, v.y, p.y), s1, c1);
        fsincos(fmaf(0.1f, v.z, p.z), s2, c2);
        fsincos(fmaf(0.1f, v.w, p.w), s3, c3);
        union { int4 v4; __half2 h[4]; } u;
        u.h[0] = __floats2half2_rn(a.x*c0, a.x*s0);
        u.h[1] = __floats2half2_rn(a.y*c1, a.y*s1);
        u.h[2] = __floats2half2_rn(a.z*c2, a.z*s2);
        u.h[3] = __floats2half2_rn(a.w*c3, a.w*s3);
        S[(size_t)node*32 + hl] = u.v4;
        float st = a.x + a.y + a.z + a.w;
        #pragma unroll
        for (int off = 16; off > 0; off >>= 1) st += __shfl_xor(st, off);
        if (hl == 0) strength[node] = st;
        return;
    }
    __shared__ float sig[HIDDEN];
    __shared__ float red[HIDDEN];
    __shared__ int fl[256];
    if (tid < HIDDEN) {
        float acc = b_in[tid];
        #pragma unroll 8
        for (int d = 0; d < IN_DIM; ++d) acc = fmaf(W_in[tid*IN_DIM + d], x[d], acc);
        sig[tid] = acc;
        red[tid] = fabsf(acc);
    }
    int v = 0;
    #pragma unroll
    for (int r = 0; r < 4; ++r) v |= (int)maskb[(tid + 256*r)*4 + 1];
    fl[tid] = v;
    __syncthreads();
    for (int s = 64; s > 0; s >>= 1) {
        if (tid < s) red[tid] = fmaxf(red[tid], red[tid + s]);
        __syncthreads();
    }
    for (int s = 128; s > 0; s >>= 1) {
        if (tid < s) fl[tid] |= fl[tid + s];
        __syncthreads();
    }
    if (tid < HIDDEN) pp[tid] = sig[tid] / (red[0] + 1e-8f) * 0.314159265358979f;
    if (tid == 0) *flag = (fl[0] != 0) ? 1 : 0;   // 1 => 1-byte bool layout
}

// k_adj: per node, compact valid edges (order-preserving) + argmax-by-strength.
// Record: adj[2i]={w0..w3}, adj[2i+1]={w4,w5, deg|(cb<<8), 0};
// w = j | sign<<24 | valid<<25. LDS-staged compaction (no scratch, rule #20).
__global__ __launch_bounds__(256) void k_adj(
    const int* __restrict__ nbr_idx, const float* __restrict__ nbr_sign,
    const void* __restrict__ nbr_mask, const int* __restrict__ flagp,
    const float* __restrict__ strength, int4* __restrict__ adj)
{
    __shared__ int   lw[256][MAX_DEG];
    __shared__ float ls[256][MAX_DEG];
    const int t = threadIdx.x;
    const int i = blockIdx.x*256 + t;
    const int flagv = *flagp;
    const unsigned char* mb = (const unsigned char*)nbr_mask;
    const int*           mi = (const int*)nbr_mask;
    int cnt = 0;
    #pragma unroll
    for (int k = 0; k < MAX_DEG; ++k) {
        const int e = i*MAX_DEG + k;
        const int m = flagv ? (mb[e] != 0) : (mi[e] != 0);
        const int j = nbr_idx[e];
        const float sg = nbr_sign[e];
        if (m) {
            lw[t][cnt] = j | ((sg < 0.0f) ? (1<<24) : 0) | (1<<25);
            ls[t][cnt] = strength[j];
            ++cnt;
        }
    }
    #pragma unroll
    for (int k = 0; k < MAX_DEG; ++k) if (k >= cnt) lw[t][k] = 0;
    int cb = 0; float bv = ls[t][0];                 // deg >= 1 always (ring fix)
    #pragma unroll
    for (int k = 1; k < MAX_DEG; ++k)
        if (k < cnt && ls[t][k] > bv) { bv = ls[t][k]; cb = k; }   // first max
    adj[2*(size_t)i    ] = make_int4(lw[t][0], lw[t][1], lw[t][2], lw[t][3]);
    adj[2*(size_t)i + 1] = make_int4(lw[t][4], lw[t][5], cnt | (cb << 8), 0);
}

// MAIN: 32 nodes/block; wave handles 2 nodes per iteration (32 lanes each,
// lane owns 4 complex h). NO prologue/barriers: adj records prefetched one
// iteration ahead; S gathers issue at iteration start; per-half deg predication.
__global__ __launch_bounds__(256) void k_mainc(
    const int4* __restrict__ S, const int4* __restrict__ adj,
    const int* __restrict__ step, const float* __restrict__ pp,
    float* __restrict__ P, float* __restrict__ p_sa, float* __restrict__ p_sa2)
{
    __shared__ float4 lredre[WPB][32], lredim[WPB][32];
    __shared__ float  lsa[WPB], lsa2[WPB];

    const int tid   = threadIdx.x;
    const int bx    = blockIdx.x;
    const int blk   = (bx & (NXCD-1)) * (NBLK/NXCD) + (bx >> 3);  // XCD-chunked
    const int node0 = blk * NPB;

    const int wv   = tid >> 6;
    const int lane = tid & 63;
    const int half = lane >> 5;
    const int lh   = lane & 31;
    const float trev = 0.1f * (float)step[0] * INV2PI;
    const float4 ppv = ((const float4*)pp)[lh];     // pp[4lh..4lh+3]

    float accre[4] = {0,0,0,0}, accim[4] = {0,0,0,0};
    float accsa = 0.f, accsa2 = 0.f;

    // prefetch adj record for iteration 0
    const int nlbase = wv*(2*CHUNK) + half;
    int4 A0n = adj[2*(size_t)(node0 + nlbase)    ];
    int4 A1n = adj[2*(size_t)(node0 + nlbase) + 1];

    #pragma unroll 1
    for (int c = 0; c < CHUNK; ++c) {
        const int nl = nlbase + 2*c;
        const int i  = node0 + nl;
        const int4 A0 = A0n, A1 = A1n;
        if (c + 1 < CHUNK) {                        // prefetch next record
            A0n = adj[2*(size_t)(i + 2)    ];
            A1n = adj[2*(size_t)(i + 2) + 1];
        }
        const int deg = A1.z & 0xFF;
        const int cb  = A1.z >> 8;
        const int slots[MAX_DEG] = {A0.x, A0.y, A0.z, A0.w, A1.x, A1.y};

        // ---- PREFETCH: self + deg neighbors (exec-masked per half) ----
        union H { int4 v4; __half2 h[4]; int w[4]; };
        H us, nb[MAX_DEG];
        us.v4 = S[(size_t)(unsigned)i*32 + lh];
        #pragma unroll
        for (int k = 0; k < MAX_DEG; ++k)
            if (k < deg) nb[k].v4 = S[(size_t)(unsigned)(slots[k] & 0xFFFF)*32 + lh];

        // ---- COMPUTE ----
        float R[4], I[4], inva[4];
        #pragma unroll
        for (int q = 0; q < 4; ++q) {
            const float2 e = __half22float2(us.h[q]);
            R[q] = e.x; I[q] = e.y;
            inva[q] = __builtin_amdgcn_rsqf(e.x*e.x + e.y*e.y);
        }

        float ir[4] = {0,0,0,0}, ii[4] = {0,0,0,0};
        #pragma unroll
        for (int k = 0; k < MAX_DEG; ++k) {
            if (k < deg) {
                const int w = slots[k];
                const float sgnm = (w & (1<<24)) ? -1.0f : 1.0f;
                #pragma unroll
                for (int q = 0; q < 4; ++q) {
                    const float2 e = __half22float2(nb[k].h[q]);
                    const float E = R[q]*e.x + I[q]*e.y;         // a_i a_j cosD
                    const float g = sgnm * E * __builtin_amdgcn_rsqf(e.x*e.x + e.y*e.y);
                    ir[q] = fmaf(g, e.x, ir[q]);
                    ii[q] = fmaf(g, e.y, ii[q]);
                }
            }
        }

        // best neighbor selected from already-loaded registers (cb < deg)
        H ub;
        #pragma unroll
        for (int q = 0; q < 4; ++q) {
            int v = nb[0].w[q];
            #pragma unroll
            for (int k = 1; k < MAX_DEG; ++k)
                if (k < deg) v = (k == cb) ? nb[k].w[q] : v;
            ub.w[q] = v;
        }

        // new = 0.7*state + (0.3*0.1/deg)*interference/a_i  (deg >= 1 always)
        const float f = 0.03f * __builtin_amdgcn_rcpf((float)deg);
        float nr[4], ni[4];
        #pragma unroll
        for (int q = 0; q < 4; ++q) {
            const float fq = f * inva[q];
            nr[q] = fmaf(0.7f, R[q], fq*ir[q]);
            ni[q] = fmaf(0.7f, I[q], fq*ii[q]);
        }

        // morphism: new += 0.02 * new*conj(src)/|new|
        if (deg >= 2) {
            #pragma unroll
            for (int q = 0; q < 4; ++q) {
                const float2 e = __half22float2(ub.h[q]);
                const float im = 0.02f * __builtin_amdgcn_rsqf(nr[q]*nr[q] + ni[q]*ni[q]);
                const float mr = im*(nr[q]*e.x + ni[q]*e.y);
                const float mi = im*(ni[q]*e.x - nr[q]*e.y);
                nr[q] += mr; ni[q] += mi;
            }
        }

        // traveling wave
        const float wr = fmaf((float)i, 1.52587890625e-5f, trev);
        const float wf = 1.0f + 0.02f * __builtin_amdgcn_sinf(wr);
        #pragma unroll
        for (int q = 0; q < 4; ++q) { nr[q] *= wf; ni[q] *= wf; }

        // input-driven phase rotation for i < 32
        if (i < 32) {
            const float fac = 0.1f / fmaf(0.1f, (float)i, 1.0f);
            const float pv[4] = {ppv.x, ppv.y, ppv.z, ppv.w};
            #pragma unroll
            for (int q = 0; q < 4; ++q) {
                float sp, cp;
                fsincos(pv[q]*fac, sp, cp);
                const float tr = nr[q]*cp - ni[q]*sp;
                ni[q] = ni[q]*cp + nr[q]*sp;
                nr[q] = tr;
            }
        }

        // amplitude renorm: cs = new/(rowmax|new|+1e-8)
        float m[4];
        #pragma unroll
        for (int q = 0; q < 4; ++q) m[q] = sqrtf(nr[q]*nr[q] + ni[q]*ni[q]);
        float lm = fmaxf(fmaxf(m[0], m[1]), fmaxf(m[2], m[3]));
        #pragma unroll
        for (int off = 16; off > 0; off >>= 1) lm = fmaxf(lm, __shfl_xor(lm, off));
        const float sc = 1.0f / (lm + 1e-8f);
        #pragma unroll
        for (int q = 0; q < 4; ++q) {
            accre[q] += nr[q]*sc;
            accim[q] += ni[q]*sc;
            const float A = m[q]*sc;
            accsa  += A;
            accsa2 += A*A;
        }
    }

    // ---- cross-half then cross-wave reduction ----
    #pragma unroll
    for (int q = 0; q < 4; ++q) {
        accre[q] += __shfl_xor(accre[q], 32);
        accim[q] += __shfl_xor(accim[q], 32);
    }
    #pragma unroll
    for (int off = 32; off > 0; off >>= 1) {
        accsa  += __shfl_xor(accsa,  off);
        accsa2 += __shfl_xor(accsa2, off);
    }
    if (half == 0) {
        lredre[wv][lh] = make_float4(accre[0], accre[1], accre[2], accre[3]);
        lredim[wv][lh] = make_float4(accim[0], accim[1], accim[2], accim[3]);
    }
    if (lane == 0) { lsa[wv] = accsa; lsa2[wv] = accsa2; }
    __syncthreads();
    if (tid < 32) {
        float4 r = lredre[0][tid], im = lredim[0][tid];
        #pragma unroll
        for (int w = 1; w < WPB; ++w) {
            const float4 a = lredre[w][tid], b = lredim[w][tid];
            r.x += a.x; r.y += a.y; r.z += a.z; r.w += a.w;
            im.x += b.x; im.y += b.y; im.z += b.z; im.w += b.w;
        }
        P[(4*tid  )*NBLK + blk]       = r.x;
        P[(4*tid+1)*NBLK + blk]       = r.y;
        P[(4*tid+2)*NBLK + blk]       = r.z;
        P[(4*tid+3)*NBLK + blk]       = r.w;
        P[(128+4*tid  )*NBLK + blk]   = im.x;
        P[(128+4*tid+1)*NBLK + blk]   = im.y;
        P[(128+4*tid+2)*NBLK + blk]   = im.z;
        P[(128+4*tid+3)*NBLK + blk]   = im.w;
    }
    if (tid == 0) {
        p_sa [blk] = lsa[0]  + lsa[1]  + lsa[2]  + lsa[3];
        p_sa2[blk] = lsa2[0] + lsa2[1] + lsa2[2] + lsa2[3];
    }
}

// ---------------- reductions ----------------
__global__ void k_red(const float* __restrict__ P, float* __restrict__ mean)
{
    __shared__ double red[256];
    const int r = blockIdx.x, tid = threadIdx.x;
    double s = 0.0;
    #pragma unroll
    for (int k = 0; k < NBLK/256; ++k) s += (double)P[(size_t)r*NBLK + tid + 256*k];
    red[tid] = s;
    __syncthreads();
    for (int st = 128; st > 0; st >>= 1) { if (tid < st) red[tid] += red[tid + st]; __syncthreads(); }
    if (tid == 0) mean[r] = (float)(red[0] / (double)N_CELLS);
}

__global__ void k_final(const float* __restrict__ mean_in,
                        const float* __restrict__ p_sa, const float* __restrict__ p_sa2,
                        const float* __restrict__ W_dec, const float* __restrict__ b_dec,
                        float* __restrict__ out)
{
    __shared__ float  mean[2*HIDDEN];
    __shared__ double dred[256];
    __shared__ double tots[2];
    const int tid = threadIdx.x;
    mean[tid] = mean_in[tid];
    double sa = 0.0, sa2 = 0.0;
    #pragma unroll
    for (int k = 0; k < NBLK/256; ++k) {
        sa  += (double)p_sa [tid + 256*k];
        sa2 += (double)p_sa2[tid + 256*k];
    }
    dred[tid] = sa;
    __syncthreads();
    for (int s = 128; s > 0; s >>= 1) { if (tid < s) dred[tid] += dred[tid + s]; __syncthreads(); }
    if (tid == 0) tots[0] = dred[0];
    __syncthreads();
    dred[tid] = sa2;
    __syncthreads();
    for (int s = 128; s > 0; s >>= 1) { if (tid < s) dred[tid] += dred[tid + s]; __syncthreads(); }
    if (tid == 0) tots[1] = dred[0];
    __syncthreads();

    if (tid < IN_DIM) {
        float acc = b_dec[tid];
        #pragma unroll 8
        for (int c = 0; c < 2*HIDDEN; ++c) acc = fmaf(mean[c], W_dec[tid*2*HIDDEN + c], acc);
        out[tid] = acc;
    }
    if (tid == 0) {
        const double M = (double)N_CELLS * (double)HIDDEN;
        const double var = (tots[1] - tots[0]*tots[0]/M) / (M - 1.0);
        out[IN_DIM] = (float)var;
    }
}

extern "C" void kernel_launch(void* const* d_in, const int* in_sizes, int n_in,
                              void* d_out, int out_size, void* d_ws, size_t ws_size,
                              hipStream_t stream)
{
    const float* x       = (const float*)d_in[0];
    const float* amp     = (const float*)d_in[1];
    const float* phase   = (const float*)d_in[2];
    const float* vel     = (const float*)d_in[3];
    const int*   nbr_idx = (const int*)d_in[4];
    const float* nbr_sgn = (const float*)d_in[5];
    const void*  nbr_msk = d_in[6];
    const float* W_in    = (const float*)d_in[7];
    const float* b_in    = (const float*)d_in[8];
    const float* W_dec   = (const float*)d_in[9];
    const float* b_dec   = (const float*)d_in[10];
    const int*   step    = (const int*)d_in[11];

    char* wsb = (char*)d_ws;
    float* pp    = (float*)(wsb + WS_PP);
    int*   flag  = (int*)  (wsb + WS_FLAG);
    float* strg  = (float*)(wsb + WS_STR);
    int4*  S     = (int4*) (wsb + WS_S);
    int4*  adjv  = (int4*) (wsb + WS_ADJ);
    float* P     = (float*)(wsb + WS_P);
    float* p_sa  = (float*)(wsb + WS_SA);
    float* p_sa2 = (float*)(wsb + WS_SA2);
    float* meanb = (float*)(wsb + WS_MEAN);
    float* out   = (float*)d_out;

    k_pre<<<N_CELLS/8 + 1, 256, 0, stream>>>(amp, phase, vel, x, W_in, b_in,
                                             (const unsigned char*)nbr_msk,
                                             S, strg, pp, flag);
    k_adj<<<N_CELLS/256, 256, 0, stream>>>(nbr_idx, nbr_sgn, nbr_msk, flag, strg, adjv);
    k_mainc<<<NBLK, 256, 0, stream>>>(S, adjv, step, pp, P, p_sa, p_sa2);
    k_red<<<256, 256, 0, stream>>>(P, meanb);
    k_final<<<1, 256, 0, stream>>>(meanb, p_sa, p_sa2, W_dec, b_dec, out);
}

// Round 10
// 67.273 us; speedup vs baseline: 1.0341x; 1.0341x over previous
//
#include <hip/hip_runtime.h>
#include <hip/hip_fp16.h>
#include <math.h>

#define N_CELLS 65536
#define HIDDEN  128
#define IN_DIM  64
#define MAX_DEG 6

#define WPB    4                    // waves per block (k_main)
#define NPB    32                   // nodes per block
#define NBLK   (N_CELLS/NPB)        // 2048 main-kernel blocks
#define CHUNK  4                    // iterations per wave (2 nodes per iter)
#define NXCD   8

#define INV2PI 0.15915494309189535f

typedef _Float16 h2f __attribute__((ext_vector_type(2)));

__device__ __forceinline__ void fsincos(float x, float& s, float& c) {
    const float r = x * INV2PI;                     // revolutions for v_sin/v_cos
    s = __builtin_amdgcn_sinf(r);
    c = __builtin_amdgcn_cosf(r);
}

// ---------------- ws offsets (~36.5 MB) ----------------
#define WS_PP    0                                  // 128 f32
#define WS_FLAG  512                                // 1 int
#define WS_STR   1024                               // 65536 f32
#define WS_S     (1024 + N_CELLS*4)                 // 65536 x 512B fp16 states (32 MB)
#define WS_ADJ   (WS_S + (size_t)N_CELLS*512)       // 65536 x 32B adj records (2 MB)
#define WS_P     (WS_ADJ + (size_t)N_CELLS*32)      // 256 x NBLK f32 (2 MB)
#define WS_SA    (WS_P + 256*NBLK*4)                // NBLK f32
#define WS_SA2   (WS_SA + NBLK*4)                   // NBLK f32
#define WS_MEAN  (WS_SA2 + NBLK*4)                  // 256 f32

// k_pre: S[i][h] = (R,I) fp16 = amp*e^{i(phase+0.1vel)}; strength[i]=sum_h amp.
// XCD-chunked block order so the XCD that WRITES S row i also READS it in
// k_mainc (producer L2 == consumer L2). Last block: prep (pp, mask flag).
__global__ __launch_bounds__(256) void k_pre(
    const float* __restrict__ amp, const float* __restrict__ phase,
    const float* __restrict__ vel,
    const float* __restrict__ x, const float* __restrict__ W_in,
    const float* __restrict__ b_in, const unsigned char* __restrict__ maskb,
    int4* __restrict__ S, float* __restrict__ strength,
    float* __restrict__ pp, int* __restrict__ flag)
{
    const int tid = threadIdx.x;
    const int bx  = blockIdx.x;
    if (bx < N_CELLS/8) {
        const int blkp = (bx & (NXCD-1)) * (N_CELLS/8/NXCD) + (bx >> 3);  // XCD-chunked
        const int node = blkp*8 + (tid >> 5);
        const int hl   = tid & 31;
        const size_t ro = (size_t)node*HIDDEN + 4*hl;
        const float4 a = *(const float4*)(amp   + ro);
        const float4 p = *(const float4*)(phase + ro);
        const float4 v = *(const float4*)(vel   + ro);
        float s0,c0,s1,c1,s2,c2,s3,c3;
        fsincos(fmaf(0.1f, v.x, p.x), s0, c0);
        fsincos(fmaf(0.1f, v.y, p.y), s1, c1);
        fsincos(fmaf(0.1f, v.z, p.z), s2, c2);
        fsincos(fmaf(0.1f, v.w, p.w), s3, c3);
        union { int4 v4; __half2 h[4]; } u;
        u.h[0] = __floats2half2_rn(a.x*c0, a.x*s0);
        u.h[1] = __floats2half2_rn(a.y*c1, a.y*s1);
        u.h[2] = __floats2half2_rn(a.z*c2, a.z*s2);
        u.h[3] = __floats2half2_rn(a.w*c3, a.w*s3);
        S[(size_t)node*32 + hl] = u.v4;
        float st = a.x + a.y + a.z + a.w;
        #pragma unroll
        for (int off = 16; off > 0; off >>= 1) st += __shfl_xor(st, off);
        if (hl == 0) strength[node] = st;
        return;
    }
    __shared__ float sig[HIDDEN];
    __shared__ float red[HIDDEN];
    __shared__ int fl[256];
    if (tid < HIDDEN) {
        float acc = b_in[tid];
        #pragma unroll 8
        for (int d = 0; d < IN_DIM; ++d) acc = fmaf(W_in[tid*IN_DIM + d], x[d], acc);
        sig[tid] = acc;
        red[tid] = fabsf(acc);
    }
    int v = 0;
    #pragma unroll
    for (int r = 0; r < 4; ++r) v |= (int)maskb[(tid + 256*r)*4 + 1];
    fl[tid] = v;
    __syncthreads();
    for (int s = 64; s > 0; s >>= 1) {
        if (tid < s) red[tid] = fmaxf(red[tid], red[tid + s]);
        __syncthreads();
    }
    for (int s = 128; s > 0; s >>= 1) {
        if (tid < s) fl[tid] |= fl[tid + s];
        __syncthreads();
    }
    if (tid < HIDDEN) pp[tid] = sig[tid] / (red[0] + 1e-8f) * 0.314159265358979f;
    if (tid == 0) *flag = (fl[0] != 0) ? 1 : 0;   // 1 => 1-byte bool layout
}

// k_adj: per node, compact valid edges (order-preserving) + argmax-by-strength.
// Record: adj[2i]={w0..w3}, adj[2i+1]={w4,w5, deg|(cb<<8), 0}. XCD-chunked.
__global__ __launch_bounds__(256) void k_adj(
    const int* __restrict__ nbr_idx, const float* __restrict__ nbr_sign,
    const void* __restrict__ nbr_mask, const int* __restrict__ flagp,
    const float* __restrict__ strength, int4* __restrict__ adj)
{
    __shared__ int   lw[256][MAX_DEG];
    __shared__ float ls[256][MAX_DEG];
    const int t = threadIdx.x;
    const int bx = blockIdx.x;
    const int blkp = (bx & (NXCD-1)) * (N_CELLS/256/NXCD) + (bx >> 3);  // XCD-chunked
    const int i = blkp*256 + t;
    const int flagv = *flagp;
    const unsigned char* mb = (const unsigned char*)nbr_mask;
    const int*           mi = (const int*)nbr_mask;
    int cnt = 0;
    #pragma unroll
    for (int k = 0; k < MAX_DEG; ++k) {
        const int e = i*MAX_DEG + k;
        const int m = flagv ? (mb[e] != 0) : (mi[e] != 0);
        const int j = nbr_idx[e];
        const float sg = nbr_sign[e];
        if (m) {
            lw[t][cnt] = j | ((sg < 0.0f) ? (1<<24) : 0) | (1<<25);
            ls[t][cnt] = strength[j];
            ++cnt;
        }
    }
    #pragma unroll
    for (int k = 0; k < MAX_DEG; ++k) if (k >= cnt) lw[t][k] = 0;
    int cb = 0; float bv = ls[t][0];                 // deg >= 1 always (ring fix)
    #pragma unroll
    for (int k = 1; k < MAX_DEG; ++k)
        if (k < cnt && ls[t][k] > bv) { bv = ls[t][k]; cb = k; }   // first max
    adj[2*(size_t)i    ] = make_int4(lw[t][0], lw[t][1], lw[t][2], lw[t][3]);
    adj[2*(size_t)i + 1] = make_int4(lw[t][4], lw[t][5], cnt | (cb << 8), 0);
}

// MAIN: 32 nodes/block; wave handles 2 nodes per iteration (32 lanes each,
// lane owns 4 complex h). No prologue; adj prefetched one iteration ahead;
// v_dot2_f32_f16 for E and |e|^2; per-half deg predication; XCD-chunked.
__global__ __launch_bounds__(256) void k_mainc(
    const int4* __restrict__ S, const int4* __restrict__ adj,
    const int* __restrict__ step, const float* __restrict__ pp,
    float* __restrict__ P, float* __restrict__ p_sa, float* __restrict__ p_sa2)
{
    __shared__ float4 lredre[WPB][32], lredim[WPB][32];
    __shared__ float  lsa[WPB], lsa2[WPB];

    const int tid   = threadIdx.x;
    const int bx    = blockIdx.x;
    const int blk   = (bx & (NXCD-1)) * (NBLK/NXCD) + (bx >> 3);  // XCD-chunked
    const int node0 = blk * NPB;

    const int wv   = tid >> 6;
    const int lane = tid & 63;
    const int half = lane >> 5;
    const int lh   = lane & 31;
    const float trev = 0.1f * (float)step[0] * INV2PI;
    const float4 ppv = ((const float4*)pp)[lh];     // pp[4lh..4lh+3]

    float accre[4] = {0,0,0,0}, accim[4] = {0,0,0,0};
    float accsa = 0.f, accsa2 = 0.f;

    // prefetch adj record for iteration 0
    const int nlbase = wv*(2*CHUNK) + half;
    int4 A0n = adj[2*(size_t)(node0 + nlbase)    ];
    int4 A1n = adj[2*(size_t)(node0 + nlbase) + 1];

    #pragma unroll 1
    for (int c = 0; c < CHUNK; ++c) {
        const int nl = nlbase + 2*c;
        const int i  = node0 + nl;
        const int4 A0 = A0n, A1 = A1n;
        if (c + 1 < CHUNK) {                        // prefetch next record
            A0n = adj[2*(size_t)(i + 2)    ];
            A1n = adj[2*(size_t)(i + 2) + 1];
        }
        const int deg = A1.z & 0xFF;
        const int cb  = A1.z >> 8;
        const int slots[MAX_DEG] = {A0.x, A0.y, A0.z, A0.w, A1.x, A1.y};

        // ---- PREFETCH: self + deg neighbors (exec-masked per half) ----
        union H { int4 v4; h2f h[4]; int w[4]; };
        H us, nb[MAX_DEG];
        us.v4 = S[(size_t)(unsigned)i*32 + lh];
        #pragma unroll
        for (int k = 0; k < MAX_DEG; ++k)
            if (k < deg) nb[k].v4 = S[(size_t)(unsigned)(slots[k] & 0xFFFF)*32 + lh];

        // ---- COMPUTE ----
        float R[4], I[4], inva[4];
        #pragma unroll
        for (int q = 0; q < 4; ++q) {
            R[q] = (float)us.h[q].x;
            I[q] = (float)us.h[q].y;
            inva[q] = __builtin_amdgcn_rsqf(
                __builtin_amdgcn_fdot2(us.h[q], us.h[q], 0.0f, false));
        }

        float ir[4] = {0,0,0,0}, ii[4] = {0,0,0,0};
        #pragma unroll
        for (int k = 0; k < MAX_DEG; ++k) {
            if (k < deg) {
                const int w = slots[k];
                const float sgnm = (w & (1<<24)) ? -1.0f : 1.0f;
                #pragma unroll
                for (int q = 0; q < 4; ++q) {
                    const float E   = __builtin_amdgcn_fdot2(us.h[q], nb[k].h[q], 0.0f, false);
                    const float aj2 = __builtin_amdgcn_fdot2(nb[k].h[q], nb[k].h[q], 0.0f, false);
                    const float g = sgnm * E * __builtin_amdgcn_rsqf(aj2);
                    ir[q] = fmaf(g, (float)nb[k].h[q].x, ir[q]);
                    ii[q] = fmaf(g, (float)nb[k].h[q].y, ii[q]);
                }
            }
        }

        // best neighbor selected from already-loaded registers (cb < deg)
        H ub;
        #pragma unroll
        for (int q = 0; q < 4; ++q) {
            int v = nb[0].w[q];
            #pragma unroll
            for (int k = 1; k < MAX_DEG; ++k)
                if (k < deg) v = (k == cb) ? nb[k].w[q] : v;
            ub.w[q] = v;
        }

        // new = 0.7*state + (0.3*0.1/deg)*interference/a_i  (deg >= 1 always)
        const float f = 0.03f * __builtin_amdgcn_rcpf((float)deg);
        float nr[4], ni[4];
        #pragma unroll
        for (int q = 0; q < 4; ++q) {
            const float fq = f * inva[q];
            nr[q] = fmaf(0.7f, R[q], fq*ir[q]);
            ni[q] = fmaf(0.7f, I[q], fq*ii[q]);
        }

        // morphism: new += 0.02 * new*conj(src)/|new|
        if (deg >= 2) {
            #pragma unroll
            for (int q = 0; q < 4; ++q) {
                const float ex = (float)ub.h[q].x, ey = (float)ub.h[q].y;
                const float im = 0.02f * __builtin_amdgcn_rsqf(nr[q]*nr[q] + ni[q]*ni[q]);
                const float mr = im*(nr[q]*ex + ni[q]*ey);
                const float mi = im*(ni[q]*ex - nr[q]*ey);
                nr[q] += mr; ni[q] += mi;
            }
        }

        // traveling wave
        const float wr = fmaf((float)i, 1.52587890625e-5f, trev);
        const float wf = 1.0f + 0.02f * __builtin_amdgcn_sinf(wr);
        #pragma unroll
        for (int q = 0; q < 4; ++q) { nr[q] *= wf; ni[q] *= wf; }

        // input-driven phase rotation for i < 32
        if (i < 32) {
            const float fac = 0.1f / fmaf(0.1f, (float)i, 1.0f);
            const float pv[4] = {ppv.x, ppv.y, ppv.z, ppv.w};
            #pragma unroll
            for (int q = 0; q < 4; ++q) {
                float sp, cp;
                fsincos(pv[q]*fac, sp, cp);
                const float tr = nr[q]*cp - ni[q]*sp;
                ni[q] = ni[q]*cp + nr[q]*sp;
                nr[q] = tr;
            }
        }

        // amplitude renorm: cs = new/(rowmax|new|+1e-8)
        float m[4];
        #pragma unroll
        for (int q = 0; q < 4; ++q) m[q] = sqrtf(nr[q]*nr[q] + ni[q]*ni[q]);
        float lm = fmaxf(fmaxf(m[0], m[1]), fmaxf(m[2], m[3]));
        #pragma unroll
        for (int off = 16; off > 0; off >>= 1) lm = fmaxf(lm, __shfl_xor(lm, off));
        const float sc = 1.0f / (lm + 1e-8f);
        #pragma unroll
        for (int q = 0; q < 4; ++q) {
            accre[q] += nr[q]*sc;
            accim[q] += ni[q]*sc;
            const float A = m[q]*sc;
            accsa  += A;
            accsa2 += A*A;
        }
    }

    // ---- cross-half then cross-wave reduction ----
    #pragma unroll
    for (int q = 0; q < 4; ++q) {
        accre[q] += __shfl_xor(accre[q], 32);
        accim[q] += __shfl_xor(accim[q], 32);
    }
    #pragma unroll
    for (int off = 32; off > 0; off >>= 1) {
        accsa  += __shfl_xor(accsa,  off);
        accsa2 += __shfl_xor(accsa2, off);
    }
    if (half == 0) {
        lredre[wv][lh] = make_float4(accre[0], accre[1], accre[2], accre[3]);
        lredim[wv][lh] = make_float4(accim[0], accim[1], accim[2], accim[3]);
    }
    if (lane == 0) { lsa[wv] = accsa; lsa2[wv] = accsa2; }
    __syncthreads();
    if (tid < 32) {
        float4 r = lredre[0][tid], im = lredim[0][tid];
        #pragma unroll
        for (int w = 1; w < WPB; ++w) {
            const float4 a = lredre[w][tid], b = lredim[w][tid];
            r.x += a.x; r.y += a.y; r.z += a.z; r.w += a.w;
            im.x += b.x; im.y += b.y; im.z += b.z; im.w += b.w;
        }
        P[(4*tid  )*NBLK + blk]       = r.x;
        P[(4*tid+1)*NBLK + blk]       = r.y;
        P[(4*tid+2)*NBLK + blk]       = r.z;
        P[(4*tid+3)*NBLK + blk]       = r.w;
        P[(128+4*tid  )*NBLK + blk]   = im.x;
        P[(128+4*tid+1)*NBLK + blk]   = im.y;
        P[(128+4*tid+2)*NBLK + blk]   = im.z;
        P[(128+4*tid+3)*NBLK + blk]   = im.w;
    }
    if (tid == 0) {
        p_sa [blk] = lsa[0]  + lsa[1]  + lsa[2]  + lsa[3];
        p_sa2[blk] = lsa2[0] + lsa2[1] + lsa2[2] + lsa2[3];
    }
}

// ---------------- reductions ----------------
__global__ void k_red(const float* __restrict__ P, float* __restrict__ mean)
{
    __shared__ double red[256];
    const int r = blockIdx.x, tid = threadIdx.x;
    double s = 0.0;
    #pragma unroll
    for (int k = 0; k < NBLK/256; ++k) s += (double)P[(size_t)r*NBLK + tid + 256*k];
    red[tid] = s;
    __syncthreads();
    for (int st = 128; st > 0; st >>= 1) { if (tid < st) red[tid] += red[tid + st]; __syncthreads(); }
    if (tid == 0) mean[r] = (float)(red[0] / (double)N_CELLS);
}

__global__ void k_final(const float* __restrict__ mean_in,
                        const float* __restrict__ p_sa, const float* __restrict__ p_sa2,
                        const float* __restrict__ W_dec, const float* __restrict__ b_dec,
                        float* __restrict__ out)
{
    __shared__ float  mean[2*HIDDEN];
    __shared__ double dred[256];
    __shared__ double tots[2];
    const int tid = threadIdx.x;
    mean[tid] = mean_in[tid];
    double sa = 0.0, sa2 = 0.0;
    #pragma unroll
    for (int k = 0; k < NBLK/256; ++k) {
        sa  += (double)p_sa [tid + 256*k];
        sa2 += (double)p_sa2[tid + 256*k];
    }
    dred[tid] = sa;
    __syncthreads();
    for (int s = 128; s > 0; s >>= 1) { if (tid < s) dred[tid] += dred[tid + s]; __syncthreads(); }
    if (tid == 0) tots[0] = dred[0];
    __syncthreads();
    dred[tid] = sa2;
    __syncthreads();
    for (int s = 128; s > 0; s >>= 1) { if (tid < s) dred[tid] += dred[tid + s]; __syncthreads(); }
    if (tid == 0) tots[1] = dred[0];
    __syncthreads();

    if (tid < IN_DIM) {
        float acc = b_dec[tid];
        #pragma unroll 8
        for (int c = 0; c < 2*HIDDEN; ++c) acc = fmaf(mean[c], W_dec[tid*2*HIDDEN + c], acc);
        out[tid] = acc;
    }
    if (tid == 0) {
        const double M = (double)N_CELLS * (double)HIDDEN;
        const double var = (tots[1] - tots[0]*tots[0]/M) / (M - 1.0);
        out[IN_DIM] = (float)var;
    }
}

extern "C" void kernel_launch(void* const* d_in, const int* in_sizes, int n_in,
                              void* d_out, int out_size, void* d_ws, size_t ws_size,
                              hipStream_t stream)
{
    const float* x       = (const float*)d_in[0];
    const float* amp     = (const float*)d_in[1];
    const float* phase   = (const float*)d_in[2];
    const float* vel     = (const float*)d_in[3];
    const int*   nbr_idx = (const int*)d_in[4];
    const float* nbr_sgn = (const float*)d_in[5];
    const void*  nbr_msk = d_in[6];
    const float* W_in    = (const float*)d_in[7];
    const float* b_in    = (const float*)d_in[8];
    const float* W_dec   = (const float*)d_in[9];
    const float* b_dec   = (const float*)d_in[10];
    const int*   step    = (const int*)d_in[11];

    char* wsb = (char*)d_ws;
    float* pp    = (float*)(wsb + WS_PP);
    int*   flag  = (int*)  (wsb + WS_FLAG);
    float* strg  = (float*)(wsb + WS_STR);
    int4*  S     = (int4*) (wsb + WS_S);
    int4*  adjv  = (int4*) (wsb + WS_ADJ);
    float* P     = (float*)(wsb + WS_P);
    float* p_sa  = (float*)(wsb + WS_SA);
    float* p_sa2 = (float*)(wsb + WS_SA2);
    float* meanb = (float*)(wsb + WS_MEAN);
    float* out   = (float*)d_out;

    k_pre<<<N_CELLS/8 + 1, 256, 0, stream>>>(amp, phase, vel, x, W_in, b_in,
                                             (const unsigned char*)nbr_msk,
                                             S, strg, pp, flag);
    k_adj<<<N_CELLS/256, 256, 0, stream>>>(nbr_idx, nbr_sgn, nbr_msk, flag, strg, adjv);
    k_mainc<<<NBLK, 256, 0, stream>>>(S, adjv, step, pp, P, p_sa, p_sa2);
    k_red<<<256, 256, 0, stream>>>(P, meanb);
    k_final<<<1, 256, 0, stream>>>(meanb, p_sa, p_sa2, W_dec, b_dec, out);
}

// Round 11
// 66.428 us; speedup vs baseline: 1.0473x; 1.0127x over previous
//
#include <hip/hip_runtime.h>
#include <hip/hip_fp16.h>
#include <math.h>

#define N_CELLS 65536
#define HIDDEN  128
#define IN_DIM  64
#define MAX_DEG 6

#define WPB    4                    // waves per block (k_main)
#define NPB    32                   // nodes per block
#define NBLK   (N_CELLS/NPB)        // 2048 main-kernel blocks
#define CHUNK  4                    // iterations per wave (2 nodes per iter)
#define NXCD   8

#define INV2PI 0.15915494309189535f

typedef _Float16 h2f __attribute__((ext_vector_type(2)));

__device__ __forceinline__ void fsincos(float x, float& s, float& c) {
    const float r = x * INV2PI;                     // revolutions for v_sin/v_cos
    s = __builtin_amdgcn_sinf(r);
    c = __builtin_amdgcn_cosf(r);
}

// ---------------- ws offsets (~36.5 MB) ----------------
#define WS_PP    0                                  // 128 f32
#define WS_FLAG  512                                // 1 int
#define WS_STR   1024                               // 65536 f32
#define WS_S     (1024 + N_CELLS*4)                 // 65536 x 512B fp16 states (32 MB)
#define WS_ADJ   (WS_S + (size_t)N_CELLS*512)       // 65536 x 32B adj records (2 MB)
#define WS_P     (WS_ADJ + (size_t)N_CELLS*32)      // 256 x NBLK f32 (2 MB)
#define WS_SA    (WS_P + 256*NBLK*4)                // NBLK f32
#define WS_SA2   (WS_SA + NBLK*4)                   // NBLK f32
#define WS_MEAN  (WS_SA2 + NBLK*4)                  // 256 f32

// k_pre: S[i][h] = (R,I) fp16 = amp*e^{i(phase+0.1vel)}; strength[i]=sum_h amp.
// XCD-chunked so producer L2 == consumer L2. Last block: prep (pp, mask flag).
__global__ __launch_bounds__(256) void k_pre(
    const float* __restrict__ amp, const float* __restrict__ phase,
    const float* __restrict__ vel,
    const float* __restrict__ x, const float* __restrict__ W_in,
    const float* __restrict__ b_in, const unsigned char* __restrict__ maskb,
    int4* __restrict__ S, float* __restrict__ strength,
    float* __restrict__ pp, int* __restrict__ flag)
{
    const int tid = threadIdx.x;
    const int bx  = blockIdx.x;
    if (bx < N_CELLS/8) {
        const int blkp = (bx & (NXCD-1)) * (N_CELLS/8/NXCD) + (bx >> 3);  // XCD-chunked
        const int node = blkp*8 + (tid >> 5);
        const int hl   = tid & 31;
        const size_t ro = (size_t)node*HIDDEN + 4*hl;
        const float4 a = *(const float4*)(amp   + ro);
        const float4 p = *(const float4*)(phase + ro);
        const float4 v = *(const float4*)(vel   + ro);
        float s0,c0,s1,c1,s2,c2,s3,c3;
        fsincos(fmaf(0.1f, v.x, p.x), s0, c0);
        fsincos(fmaf(0.1f, v.y, p.y), s1, c1);
        fsincos(fmaf(0.1f, v.z, p.z), s2, c2);
        fsincos(fmaf(0.1f, v.w, p.w), s3, c3);
        union { int4 v4; __half2 h[4]; } u;
        u.h[0] = __floats2half2_rn(a.x*c0, a.x*s0);
        u.h[1] = __floats2half2_rn(a.y*c1, a.y*s1);
        u.h[2] = __floats2half2_rn(a.z*c2, a.z*s2);
        u.h[3] = __floats2half2_rn(a.w*c3, a.w*s3);
        S[(size_t)node*32 + hl] = u.v4;
        float st = a.x + a.y + a.z + a.w;
        #pragma unroll
        for (int off = 16; off > 0; off >>= 1) st += __shfl_xor(st, off);
        if (hl == 0) strength[node] = st;
        return;
    }
    __shared__ float sig[HIDDEN];
    __shared__ float red[HIDDEN];
    __shared__ int fl[256];
    if (tid < HIDDEN) {
        float acc = b_in[tid];
        #pragma unroll 8
        for (int d = 0; d < IN_DIM; ++d) acc = fmaf(W_in[tid*IN_DIM + d], x[d], acc);
        sig[tid] = acc;
        red[tid] = fabsf(acc);
    }
    int v = 0;
    #pragma unroll
    for (int r = 0; r < 4; ++r) v |= (int)maskb[(tid + 256*r)*4 + 1];
    fl[tid] = v;
    __syncthreads();
    for (int s = 64; s > 0; s >>= 1) {
        if (tid < s) red[tid] = fmaxf(red[tid], red[tid + s]);
        __syncthreads();
    }
    for (int s = 128; s > 0; s >>= 1) {
        if (tid < s) fl[tid] |= fl[tid + s];
        __syncthreads();
    }
    if (tid < HIDDEN) pp[tid] = sig[tid] / (red[0] + 1e-8f) * 0.314159265358979f;
    if (tid == 0) *flag = (fl[0] != 0) ? 1 : 0;   // 1 => 1-byte bool layout
}

// k_adj: per node, compact valid edges + argmax-by-strength SWAPPED TO SLOT 0
// (first-max chosen before swap). Slots [deg,kmax_pair) padded with self-index
// (valid-bit 0 -> sgn weight 0; self row is L1-hot in k_mainc). Record:
// adj[2i]={w0..w3}, adj[2i+1]={w4,w5, deg, kmax_pair}; w=j|sign<<24|valid<<25.
__global__ __launch_bounds__(256) void k_adj(
    const int* __restrict__ nbr_idx, const float* __restrict__ nbr_sign,
    const void* __restrict__ nbr_mask, const int* __restrict__ flagp,
    const float* __restrict__ strength, int4* __restrict__ adj)
{
    __shared__ int   lw[256][MAX_DEG];
    __shared__ float ls[256][MAX_DEG];
    __shared__ int   ldeg[256];
    const int t = threadIdx.x;
    const int bx = blockIdx.x;
    const int blkp = (bx & (NXCD-1)) * (N_CELLS/256/NXCD) + (bx >> 3);  // XCD-chunked
    const int i = blkp*256 + t;
    const int flagv = *flagp;
    const unsigned char* mb = (const unsigned char*)nbr_mask;
    const int*           mi = (const int*)nbr_mask;
    int cnt = 0;
    #pragma unroll
    for (int k = 0; k < MAX_DEG; ++k) {
        const int e = i*MAX_DEG + k;
        const int m = flagv ? (mb[e] != 0) : (mi[e] != 0);
        const int j = nbr_idx[e];
        const float sg = nbr_sign[e];
        if (m) {
            lw[t][cnt] = j | ((sg < 0.0f) ? (1<<24) : 0) | (1<<25);
            ls[t][cnt] = strength[j];
            ++cnt;
        }
    }
    int cb = 0; float bv = ls[t][0];                 // deg >= 1 always (ring fix)
    #pragma unroll
    for (int k = 1; k < MAX_DEG; ++k)
        if (k < cnt && ls[t][k] > bv) { bv = ls[t][k]; cb = k; }   // first max
    if (cb != 0) {                                   // best edge -> slot 0
        const int tmp = lw[t][0];
        lw[t][0] = lw[t][cb];
        lw[t][cb] = tmp;
    }
    #pragma unroll
    for (int k = 0; k < MAX_DEG; ++k) if (k >= cnt) lw[t][k] = i;  // self pad, sgn0
    ldeg[t] = cnt;
    __syncthreads();
    const int kmax = max(cnt, ldeg[t ^ 1]);          // per even/odd node pair
    adj[2*(size_t)i    ] = make_int4(lw[t][0], lw[t][1], lw[t][2], lw[t][3]);
    adj[2*(size_t)i + 1] = make_int4(lw[t][4], lw[t][5], cnt, kmax);
}

// MAIN: 32 nodes/block; wave handles 2 nodes per iteration (32 lanes each,
// lane owns 4 complex h). Edge loop bound = scalar kmax (readfirstlane) ->
// no divergent guards; best neighbor IS slot 0; morphism branchless.
__global__ __launch_bounds__(256) void k_mainc(
    const int4* __restrict__ S, const int4* __restrict__ adj,
    const int* __restrict__ step, const float* __restrict__ pp,
    float* __restrict__ P, float* __restrict__ p_sa, float* __restrict__ p_sa2)
{
    __shared__ float4 lredre[WPB][32], lredim[WPB][32];
    __shared__ float  lsa[WPB], lsa2[WPB];

    const int tid   = threadIdx.x;
    const int bx    = blockIdx.x;
    const int blk   = (bx & (NXCD-1)) * (NBLK/NXCD) + (bx >> 3);  // XCD-chunked
    const int node0 = blk * NPB;

    const int wv   = tid >> 6;
    const int lane = tid & 63;
    const int half = lane >> 5;
    const int lh   = lane & 31;
    const float trev = 0.1f * (float)step[0] * INV2PI;
    const float4 ppv = ((const float4*)pp)[lh];     // pp[4lh..4lh+3]

    float accre[4] = {0,0,0,0}, accim[4] = {0,0,0,0};
    float accsa = 0.f, accsa2 = 0.f;

    // prefetch adj record for iteration 0
    const int nlbase = wv*(2*CHUNK) + half;
    int4 A0n = adj[2*(size_t)(node0 + nlbase)    ];
    int4 A1n = adj[2*(size_t)(node0 + nlbase) + 1];

    #pragma unroll 1
    for (int c = 0; c < CHUNK; ++c) {
        const int nl = nlbase + 2*c;
        const int i  = node0 + nl;
        const int4 A0 = A0n, A1 = A1n;
        if (c + 1 < CHUNK) {                        // prefetch next record
            A0n = adj[2*(size_t)(i + 2)    ];
            A1n = adj[2*(size_t)(i + 2) + 1];
        }
        const int deg  = A1.z;
        const int kmax = __builtin_amdgcn_readfirstlane(A1.w);  // wave-uniform
        const int slots[MAX_DEG] = {A0.x, A0.y, A0.z, A0.w, A1.x, A1.y};

        // ---- PREFETCH: self + kmax slots, back-to-back (scalar guards) ----
        union H { int4 v4; h2f h[4]; int w[4]; };
        H us, nb[MAX_DEG];
        us.v4 = S[(size_t)(unsigned)i*32 + lh];
        #pragma unroll
        for (int k = 0; k < MAX_DEG; ++k)
            if (k < kmax) nb[k].v4 = S[(size_t)(unsigned)(slots[k] & 0xFFFF)*32 + lh];

        // ---- COMPUTE ----
        float R[4], I[4], inva[4];
        #pragma unroll
        for (int q = 0; q < 4; ++q) {
            R[q] = (float)us.h[q].x;
            I[q] = (float)us.h[q].y;
            inva[q] = __builtin_amdgcn_rsqf(
                __builtin_amdgcn_fdot2(us.h[q], us.h[q], 0.0f, false));
        }

        float ir[4] = {0,0,0,0}, ii[4] = {0,0,0,0};
        #pragma unroll
        for (int k = 0; k < MAX_DEG; ++k) {
            if (k < kmax) {
                const int w = slots[k];
                const float vf = (float)((w >> 25) & 1);            // 0 for pads
                const float sgnm = (w & (1<<24)) ? -vf : vf;
                #pragma unroll
                for (int q = 0; q < 4; ++q) {
                    const float E   = __builtin_amdgcn_fdot2(us.h[q], nb[k].h[q], 0.0f, false);
                    const float aj2 = __builtin_amdgcn_fdot2(nb[k].h[q], nb[k].h[q], 0.0f, false);
                    const float g = sgnm * E * __builtin_amdgcn_rsqf(aj2);
                    ir[q] = fmaf(g, (float)nb[k].h[q].x, ir[q]);
                    ii[q] = fmaf(g, (float)nb[k].h[q].y, ii[q]);
                }
            }
        }

        // new = 0.7*state + (0.3*0.1/deg)*interference/a_i  (deg >= 1 always)
        const float f = 0.03f * __builtin_amdgcn_rcpf((float)deg);
        float nr[4], ni[4];
        #pragma unroll
        for (int q = 0; q < 4; ++q) {
            const float fq = f * inva[q];
            nr[q] = fmaf(0.7f, R[q], fq*ir[q]);
            ni[q] = fmaf(0.7f, I[q], fq*ii[q]);
        }

        // morphism: new += g2 * new*conj(src)/|new|, src = nb[0] (best-first)
        const float g2 = (deg >= 2) ? 0.02f : 0.0f;
        #pragma unroll
        for (int q = 0; q < 4; ++q) {
            const float ex = (float)nb[0].h[q].x, ey = (float)nb[0].h[q].y;
            const float im = g2 * __builtin_amdgcn_rsqf(
                fmaxf(nr[q]*nr[q] + ni[q]*ni[q], 1e-30f));
            const float mr = im*(nr[q]*ex + ni[q]*ey);
            const float mi = im*(ni[q]*ex - nr[q]*ey);
            nr[q] += mr; ni[q] += mi;
        }

        // traveling wave
        const float wr = fmaf((float)i, 1.52587890625e-5f, trev);
        const float wf = 1.0f + 0.02f * __builtin_amdgcn_sinf(wr);
        #pragma unroll
        for (int q = 0; q < 4; ++q) { nr[q] *= wf; ni[q] *= wf; }

        // input-driven phase rotation for i < 32
        if (i < 32) {
            const float fac = 0.1f / fmaf(0.1f, (float)i, 1.0f);
            const float pv[4] = {ppv.x, ppv.y, ppv.z, ppv.w};
            #pragma unroll
            for (int q = 0; q < 4; ++q) {
                float sp, cp;
                fsincos(pv[q]*fac, sp, cp);
                const float tr = nr[q]*cp - ni[q]*sp;
                ni[q] = ni[q]*cp + nr[q]*sp;
                nr[q] = tr;
            }
        }

        // amplitude renorm: cs = new/(rowmax|new|+1e-8)
        float m[4];
        #pragma unroll
        for (int q = 0; q < 4; ++q) m[q] = sqrtf(nr[q]*nr[q] + ni[q]*ni[q]);
        float lm = fmaxf(fmaxf(m[0], m[1]), fmaxf(m[2], m[3]));
        #pragma unroll
        for (int off = 16; off > 0; off >>= 1) lm = fmaxf(lm, __shfl_xor(lm, off));
        const float sc = 1.0f / (lm + 1e-8f);
        #pragma unroll
        for (int q = 0; q < 4; ++q) {
            accre[q] += nr[q]*sc;
            accim[q] += ni[q]*sc;
            const float A = m[q]*sc;
            accsa  += A;
            accsa2 += A*A;
        }
    }

    // ---- cross-half then cross-wave reduction ----
    #pragma unroll
    for (int q = 0; q < 4; ++q) {
        accre[q] += __shfl_xor(accre[q], 32);
        accim[q] += __shfl_xor(accim[q], 32);
    }
    #pragma unroll
    for (int off = 32; off > 0; off >>= 1) {
        accsa  += __shfl_xor(accsa,  off);
        accsa2 += __shfl_xor(accsa2, off);
    }
    if (half == 0) {
        lredre[wv][lh] = make_float4(accre[0], accre[1], accre[2], accre[3]);
        lredim[wv][lh] = make_float4(accim[0], accim[1], accim[2], accim[3]);
    }
    if (lane == 0) { lsa[wv] = accsa; lsa2[wv] = accsa2; }
    __syncthreads();
    if (tid < 32) {
        float4 r = lredre[0][tid], im = lredim[0][tid];
        #pragma unroll
        for (int w = 1; w < WPB; ++w) {
            const float4 a = lredre[w][tid], b = lredim[w][tid];
            r.x += a.x; r.y += a.y; r.z += a.z; r.w += a.w;
            im.x += b.x; im.y += b.y; im.z += b.z; im.w += b.w;
        }
        P[(4*tid  )*NBLK + blk]       = r.x;
        P[(4*tid+1)*NBLK + blk]       = r.y;
        P[(4*tid+2)*NBLK + blk]       = r.z;
        P[(4*tid+3)*NBLK + blk]       = r.w;
        P[(128+4*tid  )*NBLK + blk]   = im.x;
        P[(128+4*tid+1)*NBLK + blk]   = im.y;
        P[(128+4*tid+2)*NBLK + blk]   = im.z;
        P[(128+4*tid+3)*NBLK + blk]   = im.w;
    }
    if (tid == 0) {
        p_sa [blk] = lsa[0]  + lsa[1]  + lsa[2]  + lsa[3];
        p_sa2[blk] = lsa2[0] + lsa2[1] + lsa2[2] + lsa2[3];
    }
}

// ---------------- reductions ----------------
__global__ void k_red(const float* __restrict__ P, float* __restrict__ mean)
{
    __shared__ double red[256];
    const int r = blockIdx.x, tid = threadIdx.x;
    double s = 0.0;
    #pragma unroll
    for (int k = 0; k < NBLK/256; ++k) s += (double)P[(size_t)r*NBLK + tid + 256*k];
    red[tid] = s;
    __syncthreads();
    for (int st = 128; st > 0; st >>= 1) { if (tid < st) red[tid] += red[tid + st]; __syncthreads(); }
    if (tid == 0) mean[r] = (float)(red[0] / (double)N_CELLS);
}

__global__ void k_final(const float* __restrict__ mean_in,
                        const float* __restrict__ p_sa, const float* __restrict__ p_sa2,
                        const float* __restrict__ W_dec, const float* __restrict__ b_dec,
                        float* __restrict__ out)
{
    __shared__ float  mean[2*HIDDEN];
    __shared__ double dred[256];
    __shared__ double tots[2];
    const int tid = threadIdx.x;
    mean[tid] = mean_in[tid];
    double sa = 0.0, sa2 = 0.0;
    #pragma unroll
    for (int k = 0; k < NBLK/256; ++k) {
        sa  += (double)p_sa [tid + 256*k];
        sa2 += (double)p_sa2[tid + 256*k];
    }
    dred[tid] = sa;
    __syncthreads();
    for (int s = 128; s > 0; s >>= 1) { if (tid < s) dred[tid] += dred[tid + s]; __syncthreads(); }
    if (tid == 0) tots[0] = dred[0];
    __syncthreads();
    dred[tid] = sa2;
    __syncthreads();
    for (int s = 128; s > 0; s >>= 1) { if (tid < s) dred[tid] += dred[tid + s]; __syncthreads(); }
    if (tid == 0) tots[1] = dred[0];
    __syncthreads();

    if (tid < IN_DIM) {
        float acc = b_dec[tid];
        #pragma unroll 8
        for (int c = 0; c < 2*HIDDEN; ++c) acc = fmaf(mean[c], W_dec[tid*2*HIDDEN + c], acc);
        out[tid] = acc;
    }
    if (tid == 0) {
        const double M = (double)N_CELLS * (double)HIDDEN;
        const double var = (tots[1] - tots[0]*tots[0]/M) / (M - 1.0);
        out[IN_DIM] = (float)var;
    }
}

extern "C" void kernel_launch(void* const* d_in, const int* in_sizes, int n_in,
                              void* d_out, int out_size, void* d_ws, size_t ws_size,
                              hipStream_t stream)
{
    const float* x       = (const float*)d_in[0];
    const float* amp     = (const float*)d_in[1];
    const float* phase   = (const float*)d_in[2];
    const float* vel     = (const float*)d_in[3];
    const int*   nbr_idx = (const int*)d_in[4];
    const float* nbr_sgn = (const float*)d_in[5];
    const void*  nbr_msk = d_in[6];
    const float* W_in    = (const float*)d_in[7];
    const float* b_in    = (const float*)d_in[8];
    const float* W_dec   = (const float*)d_in[9];
    const float* b_dec   = (const float*)d_in[10];
    const int*   step    = (const int*)d_in[11];

    char* wsb = (char*)d_ws;
    float* pp    = (float*)(wsb + WS_PP);
    int*   flag  = (int*)  (wsb + WS_FLAG);
    float* strg  = (float*)(wsb + WS_STR);
    int4*  S     = (int4*) (wsb + WS_S);
    int4*  adjv  = (int4*) (wsb + WS_ADJ);
    float* P     = (float*)(wsb + WS_P);
    float* p_sa  = (float*)(wsb + WS_SA);
    float* p_sa2 = (float*)(wsb + WS_SA2);
    float* meanb = (float*)(wsb + WS_MEAN);
    float* out   = (float*)d_out;

    k_pre<<<N_CELLS/8 + 1, 256, 0, stream>>>(amp, phase, vel, x, W_in, b_in,
                                             (const unsigned char*)nbr_msk,
                                             S, strg, pp, flag);
    k_adj<<<N_CELLS/256, 256, 0, stream>>>(nbr_idx, nbr_sgn, nbr_msk, flag, strg, adjv);
    k_mainc<<<NBLK, 256, 0, stream>>>(S, adjv, step, pp, P, p_sa, p_sa2);
    k_red<<<256, 256, 0, stream>>>(P, meanb);
    k_final<<<1, 256, 0, stream>>>(meanb, p_sa, p_sa2, W_dec, b_dec, out);
}